// Round 2
// baseline (4946.804 us; speedup 1.0000x reference)
//
#include <hip/hip_runtime.h>
#include <math.h>

#define NTOT   131072
#define NPG    256
#define BGR    512
#define HID    128
#define EDG    2097152
#define CAP    48          // max in-degree ~40; P(>=48) negligible
#define KTOP   60
#define TLDIM  385

// ---------------- graph build ----------------
__global__ __launch_bounds__(256) void k_init(int* __restrict__ cnt) {
    int i = blockIdx.x * 256 + threadIdx.x;
    if (i < NTOT) cnt[i] = 0;
}

__global__ __launch_bounds__(256) void k_build(const int* __restrict__ ei,
                                               int* __restrict__ cnt,
                                               int* __restrict__ adjs) {
    int e = blockIdx.x * 256 + threadIdx.x;
    if (e >= EDG) return;
    int dst = ei[EDG + e];                 // edge_index[1][e]
    int pos = atomicAdd(&cnt[dst], 1);
    if (pos < CAP) adjs[(size_t)dst * CAP + pos] = e;
}

// sort each node's edge ids ascending (deterministic sum order), deg -> dinv
__global__ __launch_bounds__(256) void k_sortdeg(const float* __restrict__ ew,
                                                 int* __restrict__ adjs,
                                                 int* __restrict__ cnt,
                                                 float* __restrict__ dinv) {
    int n = blockIdx.x * 256 + threadIdx.x;
    if (n >= NTOT) return;
    int m = cnt[n];
    if (m > CAP) { m = CAP; cnt[n] = CAP; }
    int* a = adjs + (size_t)n * CAP;
    for (int i = 1; i < m; i++) {
        int key = a[i]; int j = i - 1;
        while (j >= 0 && a[j] > key) { a[j + 1] = a[j]; j--; }
        a[j + 1] = key;
    }
    float s = 0.f;
    for (int i = 0; i < m; i++) s += ew[a[i]];
    dinv[n] = 1.0f / sqrtf(s + 1.0f);       // self-loop weight appended last (ref order)
}

// rewrite adjacency: edge id -> (LOCAL src, norm)
__global__ __launch_bounds__(256) void k_fin(const int* __restrict__ ei,
                                             const float* __restrict__ ew,
                                             const float* __restrict__ dinv,
                                             const int* __restrict__ cnt,
                                             int* __restrict__ adjs,
                                             float* __restrict__ adjw) {
    int n = blockIdx.x * 256 + threadIdx.x;
    if (n >= NTOT) return;
    int m = cnt[n];
    float dn = dinv[n];
    for (int i = 0; i < m; i++) {
        int e = adjs[(size_t)n * CAP + i];
        int s = ei[e];                       // edge_index[0][e] (same graph as n)
        adjs[(size_t)n * CAP + i] = s & (NPG - 1);           // local id within graph
        adjw[(size_t)n * CAP + i] = dinv[s] * ew[e] * dn;    // (dinv[src]*ew)*dinv[dst]
    }
}

// ---------------- fused 3-layer GCN + scalar layer + key + top-60 ----------------
template<bool L0>
__device__ __forceinline__ void do_agg(float4 (&acc)[32],
                                       const float4* __restrict__ base4,
                                       const int* __restrict__ zidx,
                                       const int* __restrict__ as,
                                       const float* __restrict__ aw,
                                       int m, int nl, float dv) {
    for (int j = 0; j < m; j++) {
        int sl = as[j];
        float w = aw[j];
        const float4* r = base4 + ((size_t)(L0 ? zidx[sl] : sl)) * 32;
#pragma unroll
        for (int q = 0; q < 32; q++) {
            float4 v = r[q];
            acc[q].x += w * v.x; acc[q].y += w * v.y;
            acc[q].z += w * v.z; acc[q].w += w * v.w;
        }
    }
    float ws = dv * dv;                      // self-loop, added last (ref order)
    const float4* r = base4 + ((size_t)(L0 ? zidx[nl] : nl)) * 32;
#pragma unroll
    for (int q = 0; q < 32; q++) {
        float4 v = r[q];
        acc[q].x += ws * v.x; acc[q].y += ws * v.y;
        acc[q].z += ws * v.z; acc[q].w += ws * v.w;
    }
}

// out_row = tanh(acc @ W + b); optionally returns dot(out_row, W3)
template<bool LAST>
__device__ __forceinline__ float gemm_row(const float4 (&acc)[32],
                                          const float* __restrict__ W,
                                          const float* __restrict__ b,
                                          const float* __restrict__ W3,
                                          float* __restrict__ Xout, int n) {
    float t3 = 0.f;
    for (int jc = 0; jc < 8; jc++) {         // 16 output cols per chunk
        float o[16];
#pragma unroll
        for (int jj = 0; jj < 16; jj++) o[jj] = 0.f;
#pragma unroll
        for (int k4 = 0; k4 < 32; k4++) {    // k ascending: k = k4*4 + {0,1,2,3}
            float4 a = acc[k4];
            const float* wr = W + (size_t)(k4 * 4) * HID + jc * 16;  // uniform -> s_load
#pragma unroll
            for (int jj = 0; jj < 16; jj++) o[jj] += a.x * wr[jj];
#pragma unroll
            for (int jj = 0; jj < 16; jj++) o[jj] += a.y * wr[HID + jj];
#pragma unroll
            for (int jj = 0; jj < 16; jj++) o[jj] += a.z * wr[2 * HID + jj];
#pragma unroll
            for (int jj = 0; jj < 16; jj++) o[jj] += a.w * wr[3 * HID + jj];
        }
#pragma unroll
        for (int jj = 0; jj < 16; jj++) {
            o[jj] = tanhf(o[jj] + b[jc * 16 + jj]);
            if (LAST) t3 += o[jj] * W3[jc * 16 + jj];
        }
        float4* dst = (float4*)(Xout + (size_t)n * HID + jc * 16);
#pragma unroll
        for (int j4 = 0; j4 < 4; j4++)
            dst[j4] = make_float4(o[j4 * 4], o[j4 * 4 + 1], o[j4 * 4 + 2], o[j4 * 4 + 3]);
    }
    return t3;
}

__global__ __launch_bounds__(256, 2) void k_gnn(
        const float* __restrict__ zt, const int* __restrict__ z,
        const float* __restrict__ W0, const float* __restrict__ b0,
        const float* __restrict__ W1, const float* __restrict__ b1,
        const float* __restrict__ W2, const float* __restrict__ b2,
        const float* __restrict__ W3, const float* __restrict__ b3,
        const int* __restrict__ cnt, const int* __restrict__ adjs,
        const float* __restrict__ adjw, const float* __restrict__ dinv,
        float* __restrict__ X0, float* __restrict__ X1, float* __restrict__ X2,
        float* __restrict__ keyb, int* __restrict__ sel) {
    __shared__ int   zidx[NPG];
    __shared__ float dvs[NPG];
    __shared__ float t3s[NPG];
    __shared__ float ks[NPG];
    int t = threadIdx.x, g = blockIdx.x;
    int gbase = g * NPG;
    int n = gbase + t;
    zidx[t] = z[n];
    dvs[t]  = dinv[n];
    __syncthreads();

    int m = cnt[n]; if (m > CAP) m = CAP;
    const int*   as = adjs + (size_t)n * CAP;
    const float* aw = adjw + (size_t)n * CAP;
    float dv = dvs[t];
    float4 acc[32];

    // ---- layer 0 (gather straight from z_table via LDS-cached indices) ----
#pragma unroll
    for (int q = 0; q < 32; q++) acc[q] = make_float4(0.f, 0.f, 0.f, 0.f);
    do_agg<true>(acc, (const float4*)zt, zidx, as, aw, m, t, dv);
    gemm_row<false>(acc, W0, b0, nullptr, X0, n);
    __syncthreads();

    // ---- layer 1 ----
#pragma unroll
    for (int q = 0; q < 32; q++) acc[q] = make_float4(0.f, 0.f, 0.f, 0.f);
    do_agg<false>(acc, (const float4*)X0 + (size_t)gbase * 32, zidx, as, aw, m, t, dv);
    gemm_row<false>(acc, W1, b1, nullptr, X1, n);
    __syncthreads();

    // ---- layer 2 (+ dot with W3 on the fly) ----
#pragma unroll
    for (int q = 0; q < 32; q++) acc[q] = make_float4(0.f, 0.f, 0.f, 0.f);
    do_agg<false>(acc, (const float4*)X1 + (size_t)gbase * 32, zidx, as, aw, m, t, dv);
    float t3 = gemm_row<true>(acc, W2, b2, W3, X2, n);
    t3s[t] = t3;
    __syncthreads();

    // ---- layer 3: scalar aggregation + tanh -> sort key ----
    float s = 0.f;
    for (int j = 0; j < m; j++) s += aw[j] * t3s[as[j]];
    s += dv * dv * t3s[t];
    float key = tanhf(s + b3[0]);
    keyb[n] = key;
    ks[t] = key;
    __syncthreads();

    // ---- stable top-60 (exact argsort-descending semantics) ----
    int rank = 0;
    for (int j = 0; j < NPG; j++) {
        float kj = ks[j];
        rank += (kj > key) || (kj == key && j < t);
    }
    if (rank < KTOP) sel[g * KTOP + rank] = n;
}

// ---------------- conv/MLP head: one block per graph ----------------
__global__ __launch_bounds__(256) void k_head(const float* __restrict__ X0,
                                              const float* __restrict__ X1,
                                              const float* __restrict__ X2,
                                              const float* __restrict__ key,
                                              const int* __restrict__ sel,
                                              const float* __restrict__ c1w,
                                              const float* __restrict__ c1b,
                                              const float* __restrict__ c2w,
                                              const float* __restrict__ c2b,
                                              const float* __restrict__ l1w,
                                              const float* __restrict__ l1b,
                                              const float* __restrict__ l2w,
                                              const float* __restrict__ l2b,
                                              float* __restrict__ out) {
    __shared__ __align__(16) float pch[KTOP * 132];   // pooled chunk, stride 132
    __shared__ __align__(16) float w1s[16 * 132];
    __shared__ int   seln[KTOP];
    __shared__ float selk[KTOP];
    __shared__ float c1s[16 * KTOP];
    __shared__ float mps[16 * 30];
    __shared__ float w2s[32 * 80];
    __shared__ float yb[832];
    __shared__ float l1p[256];
    __shared__ float l1v[128];

    int g = blockIdx.x, t = threadIdx.x;
    if (t < KTOP) {
        int nd = sel[g * KTOP + t];
        seln[t] = nd;
        selk[t] = key[nd];
    }

    float acc1[4] = {0.f, 0.f, 0.f, 0.f};
    for (int tc = 0; tc < 3; tc++) {
        const float* Xsrc = (tc == 0) ? X0 : ((tc == 1) ? X1 : X2);
        __syncthreads();
        for (int i = t; i < KTOP * 32; i += 256) {
            int k = i >> 5, q = i & 31;
            int nd = seln[k];
            *((float4*)&pch[k * 132 + q * 4]) = ((const float4*)Xsrc)[(size_t)nd * 32 + q];
        }
        for (int i = t; i < 16 * 128; i += 256) {
            int ch = i >> 7, tt = i & 127;
            w1s[ch * 132 + tt] = c1w[ch * TLDIM + tc * 128 + tt];
        }
        __syncthreads();
#pragma unroll
        for (int it = 0; it < 4; it++) {
            int e = it * 256 + t;
            if (e < 960) {                        // e = k*16 + ch
                int k = e >> 4, ch = e & 15;
                const float* pr = &pch[k * 132];
                const float* wr = &w1s[ch * 132];
                float s = 0.f;
#pragma unroll
                for (int q = 0; q < 32; q++) {
                    float4 pv = *((float4*)&pr[q * 4]);
                    float4 wv = *((float4*)&wr[q * 4]);
                    s += pv.x * wv.x + pv.y * wv.y + pv.z * wv.z + pv.w * wv.w;
                }
                acc1[it] += s;
            }
        }
    }
    __syncthreads();
#pragma unroll
    for (int it = 0; it < 4; it++) {
        int e = it * 256 + t;
        if (e < 960) {
            int k = e >> 4, ch = e & 15;
            float v = acc1[it] + selk[k] * c1w[ch * TLDIM + 384] + c1b[ch];
            c1s[ch * KTOP + k] = fmaxf(v, 0.f);
        }
    }
    for (int i = t; i < 2560; i += 256) w2s[i] = c2w[i];
    __syncthreads();
    for (int i = t; i < 480; i += 256) {
        int ch = i / 30, p = i - ch * 30;
        mps[ch * 30 + p] = fmaxf(c1s[ch * KTOP + 2 * p], c1s[ch * KTOP + 2 * p + 1]);
    }
    __syncthreads();
    for (int e = t; e < 832; e += 256) {
        int oc = e / 26, q = e - oc * 26;
        float s = 0.f;
#pragma unroll
        for (int ic = 0; ic < 16; ic++) {
            const float* mr = &mps[ic * 30 + q];
            const float* wr = &w2s[oc * 80 + ic * 5];
#pragma unroll
            for (int j = 0; j < 5; j++) s += mr[j] * wr[j];
        }
        yb[e] = fmaxf(s + c2b[oc], 0.f);
    }
    __syncthreads();
    {
        int u = t & 127, h = t >> 7;
        float s = 0.f;
        for (int d = h * 416; d < h * 416 + 416; d++) s += yb[d] * l1w[d * 128 + u];
        l1p[t] = s;
    }
    __syncthreads();
    if (t < 128) {
        float v = fmaxf(l1p[t] + l1p[t + 128] + l1b[t], 0.f);
        l1v[t] = v * l2w[t];
    }
    __syncthreads();
    if (t < 64) {
        float v = l1v[t] + l1v[t + 64];
        v += __shfl_down(v, 32);
        v += __shfl_down(v, 16);
        v += __shfl_down(v, 8);
        v += __shfl_down(v, 4);
        v += __shfl_down(v, 2);
        v += __shfl_down(v, 1);
        if (t == 0) out[g] = v + l2b[0];
    }
}

extern "C" void kernel_launch(void* const* d_in, const int* in_sizes, int n_in,
                              void* d_out, int out_size, void* d_ws, size_t ws_size,
                              hipStream_t stream) {
    (void)in_sizes; (void)n_in; (void)out_size; (void)ws_size;
    const float* zt  = (const float*)d_in[0];
    const float* W0  = (const float*)d_in[1];
    const float* b0  = (const float*)d_in[2];
    const float* W1  = (const float*)d_in[3];
    const float* b1  = (const float*)d_in[4];
    const float* W2  = (const float*)d_in[5];
    const float* b2  = (const float*)d_in[6];
    const float* W3  = (const float*)d_in[7];
    const float* b3  = (const float*)d_in[8];
    const float* c1w = (const float*)d_in[9];
    const float* c1b = (const float*)d_in[10];
    const float* c2w = (const float*)d_in[11];
    const float* c2b = (const float*)d_in[12];
    const float* l1w = (const float*)d_in[13];
    const float* l1b = (const float*)d_in[14];
    const float* l2w = (const float*)d_in[15];
    const float* l2b = (const float*)d_in[16];
    const float* ew  = (const float*)d_in[17];
    const int*   z   = (const int*)d_in[18];
    const int*   ei  = (const int*)d_in[19];
    float* out = (float*)d_out;

    char* wsp = (char*)d_ws;
    size_t off = 0;
    auto alloc = [&](size_t bytes) -> void* {
        void* p = wsp + off;
        off += (bytes + 255) & ~(size_t)255;
        return p;
    };
    float* dinv = (float*)alloc((size_t)NTOT * 4);
    int*   cnt  = (int*)  alloc((size_t)NTOT * 4);
    int*   adjs = (int*)  alloc((size_t)NTOT * CAP * 4);
    float* adjw = (float*)alloc((size_t)NTOT * CAP * 4);
    float* X0   = (float*)alloc((size_t)NTOT * HID * 4);
    float* X1   = (float*)alloc((size_t)NTOT * HID * 4);
    float* X2   = (float*)alloc((size_t)NTOT * HID * 4);
    float* keyb = (float*)alloc((size_t)NTOT * 4);
    int*   sel  = (int*)  alloc((size_t)BGR * KTOP * 4);

    dim3 b256(256);
    k_init   <<<NTOT / 256, b256, 0, stream>>>(cnt);
    k_build  <<<EDG / 256,  b256, 0, stream>>>(ei, cnt, adjs);
    k_sortdeg<<<NTOT / 256, b256, 0, stream>>>(ew, adjs, cnt, dinv);
    k_fin    <<<NTOT / 256, b256, 0, stream>>>(ei, ew, dinv, cnt, adjs, adjw);
    k_gnn    <<<BGR,        b256, 0, stream>>>(zt, z, W0, b0, W1, b1, W2, b2, W3, b3,
                                               cnt, adjs, adjw, dinv,
                                               X0, X1, X2, keyb, sel);
    k_head   <<<BGR,        b256, 0, stream>>>(X0, X1, X2, keyb, sel,
                                               c1w, c1b, c2w, c2b,
                                               l1w, l1b, l2w, l2b, out);
}

// Round 3
// 1145.377 us; speedup vs baseline: 4.3189x; 4.3189x over previous
//
#include <hip/hip_runtime.h>
#include <math.h>

#define NTOT   131072
#define NPG    256
#define BGR    512
#define HID    128
#define EDG    2097152
#define CAP    48          // max in-degree; round-1 validated (passed exact check)
#define KTOP   60
#define TLDIM  385

// ---------------- graph build ----------------
__global__ __launch_bounds__(256) void k_init(int* __restrict__ cnt) {
    int i = blockIdx.x * 256 + threadIdx.x;
    if (i < NTOT) cnt[i] = 0;
}

__global__ __launch_bounds__(256) void k_build(const int* __restrict__ ei,
                                               int* __restrict__ cnt,
                                               int* __restrict__ adjs) {
    int e = blockIdx.x * 256 + threadIdx.x;
    if (e >= EDG) return;
    int dst = ei[EDG + e];                 // edge_index[1][e]
    int pos = atomicAdd(&cnt[dst], 1);
    if (pos < CAP) adjs[(size_t)dst * CAP + pos] = e;
}

// sort each node's edge ids ascending (deterministic sum order), compute deg
__global__ __launch_bounds__(256) void k_sortdeg(const float* __restrict__ ew,
                                                 int* __restrict__ adjs,
                                                 int* __restrict__ cnt,
                                                 float* __restrict__ deg) {
    int n = blockIdx.x * 256 + threadIdx.x;
    if (n >= NTOT) return;
    int m = cnt[n];
    if (m > CAP) { m = CAP; cnt[n] = CAP; }
    int* a = adjs + (size_t)n * CAP;
    for (int i = 1; i < m; i++) {
        int key = a[i]; int j = i - 1;
        while (j >= 0 && a[j] > key) { a[j + 1] = a[j]; j--; }
        a[j + 1] = key;
    }
    float s = 0.f;
    for (int i = 0; i < m; i++) s += ew[a[i]];
    deg[n] = s + 1.0f;                      // self-loop weight appended last (ref order)
}

__global__ __launch_bounds__(256) void k_dinv(float* __restrict__ deg) {
    int n = blockIdx.x * 256 + threadIdx.x;
    if (n < NTOT) deg[n] = 1.0f / sqrtf(deg[n]);   // deg >= 1 always
}

// rewrite adjacency: edge id -> (src, norm)
__global__ __launch_bounds__(256) void k_fin(const int* __restrict__ ei,
                                             const float* __restrict__ ew,
                                             const float* __restrict__ dinv,
                                             const int* __restrict__ cnt,
                                             int* __restrict__ adjs,
                                             float* __restrict__ adjw) {
    int n = blockIdx.x * 256 + threadIdx.x;
    if (n >= NTOT) return;
    int m = cnt[n];
    float dn = dinv[n];
    for (int i = 0; i < m; i++) {
        int e = adjs[(size_t)n * CAP + i];
        int s = ei[e];                       // edge_index[0][e]
        adjs[(size_t)n * CAP + i] = s;
        adjw[(size_t)n * CAP + i] = dinv[s] * ew[e] * dn;  // (dinv[src]*ew)*dinv[dst]
    }
}

// ---------------- embedding gather (XCD-affine: graph g -> XCD g&7) ----------------
__global__ __launch_bounds__(256) void k_embed(const float* __restrict__ zt,
                                               const int* __restrict__ z,
                                               float* __restrict__ X) {
    // 16384 blocks; 8 nodes per block; graph = (i>>5)<<3 | (b&7)
    int b = blockIdx.x;
    int x = b & 7, i = b >> 3;
    int chunk = i & 31, gg = i >> 5;
    int graph = (gg << 3) | x;
    int nbase = graph * NPG + chunk * 8;
    int t = threadIdx.x;
    int n = nbase + (t >> 5), q = t & 31;
    int zi = z[n];
    ((float4*)X)[(size_t)n * 32 + q] = ((const float4*)zt)[(size_t)zi * 32 + q];
}

// ---------------- fused GCN layer: agg(x) then @W + b, tanh ----------------
// XCD-affine swizzle: all 4 blocks of graph g land on XCD g&7 so the graph's
// X rows are fetched into ONE L2 (round-1 counters: 348MB/layer = ~4x dup).
__global__ __launch_bounds__(256) void k_layer(const float* __restrict__ Xin,
                                               float* __restrict__ Xout,
                                               const int* __restrict__ cnt,
                                               const int* __restrict__ adjs,
                                               const float* __restrict__ adjw,
                                               const float* __restrict__ dinv,
                                               const float* __restrict__ W,
                                               const float* __restrict__ bias) {
    __shared__ float agg[64][129];                 // stride 129 -> conflict-free reads
    __shared__ __align__(16) float WL[32 * 128];   // one 32-k chunk of W
    int t = threadIdx.x;
    int b = blockIdx.x;
    int x = b & 7, i = b >> 3;
    int chunk = i & 3, gg = i >> 2;
    int graph = (gg << 3) | x;
    int base = graph * NPG + chunk * 64;

    // ---- step 1: aggregate 64 rows (4 threads per node, 32 channels each) ----
    {
        int local = t >> 2;
        int node  = base + local;
        int c4    = (t & 3) * 8;                   // float4 index within row
        float4 acc[8];
#pragma unroll
        for (int q = 0; q < 8; q++) acc[q] = make_float4(0.f, 0.f, 0.f, 0.f);
        int m = cnt[node];
        if (m > CAP) m = CAP;
        const int*   as = adjs + (size_t)node * CAP;
        const float* aw = adjw + (size_t)node * CAP;
        for (int j = 0; j < m; j++) {
            int s = as[j];
            float wgt = aw[j];
            const float4* r = ((const float4*)Xin) + (size_t)s * 32 + c4;
#pragma unroll
            for (int q = 0; q < 8; q++) {
                float4 v = r[q];
                acc[q].x += wgt * v.x; acc[q].y += wgt * v.y;
                acc[q].z += wgt * v.z; acc[q].w += wgt * v.w;
            }
        }
        float dv = dinv[node];
        float ws = dv * dv;                        // self-loop norm, added last (ref order)
        const float4* r = ((const float4*)Xin) + (size_t)node * 32 + c4;
#pragma unroll
        for (int q = 0; q < 8; q++) {
            float4 v = r[q];
            acc[q].x += ws * v.x; acc[q].y += ws * v.y;
            acc[q].z += ws * v.z; acc[q].w += ws * v.w;
        }
#pragma unroll
        for (int q = 0; q < 8; q++) {
            int c = (c4 + q) * 4;
            agg[local][c + 0] = acc[q].x; agg[local][c + 1] = acc[q].y;
            agg[local][c + 2] = acc[q].z; agg[local][c + 3] = acc[q].w;
        }
    }

    // ---- step 2: 64x128 (LDS) @ 128x128 (W), each thread 8 rows x 4 cols ----
    int rg = t & 7, cg = t >> 3;                   // rows rg*8..rg*8+7, cols cg*4..+3
    float a2[8][4];
#pragma unroll
    for (int i2 = 0; i2 < 8; i2++)
#pragma unroll
        for (int j = 0; j < 4; j++) a2[i2][j] = 0.f;

    for (int kc = 0; kc < 4; kc++) {
        __syncthreads();                            // step1 done / prev chunk consumed
        const float4* Wg = (const float4*)(W + kc * 32 * HID);
#pragma unroll
        for (int i2 = 0; i2 < 4; i2++) ((float4*)WL)[t + 256 * i2] = Wg[t + 256 * i2];
        __syncthreads();
#pragma unroll
        for (int kk = 0; kk < 32; kk++) {
            float4 wv = *((float4*)&WL[kk * 128 + cg * 4]);
            float av[8];
#pragma unroll
            for (int i2 = 0; i2 < 8; i2++) av[i2] = agg[rg * 8 + i2][kc * 32 + kk];
#pragma unroll
            for (int i2 = 0; i2 < 8; i2++) {
                a2[i2][0] += av[i2] * wv.x; a2[i2][1] += av[i2] * wv.y;
                a2[i2][2] += av[i2] * wv.z; a2[i2][3] += av[i2] * wv.w;
            }
        }
    }

    float4 bv = *((const float4*)&bias[cg * 4]);
#pragma unroll
    for (int i2 = 0; i2 < 8; i2++) {
        int row = base + rg * 8 + i2;
        float4 o;
        o.x = tanhf(a2[i2][0] + bv.x); o.y = tanhf(a2[i2][1] + bv.y);
        o.z = tanhf(a2[i2][2] + bv.z); o.w = tanhf(a2[i2][3] + bv.w);
        *((float4*)&Xout[(size_t)row * HID + cg * 4]) = o;
    }
}

// ---------------- layer 3 (128 -> 1): dot then scalar aggregation ----------------
__global__ __launch_bounds__(256) void k_dot3(const float* __restrict__ X2,
                                              const float* __restrict__ W3,
                                              float* __restrict__ t3) {
    int t = threadIdx.x;
    int n = blockIdx.x * 64 + (t >> 2);
    int part = t & 3;
    const float4* r = ((const float4*)X2) + (size_t)n * 32 + part * 8;
    const float4* w = ((const float4*)W3) + part * 8;
    float s = 0.f;
#pragma unroll
    for (int q = 0; q < 8; q++) {
        float4 v = r[q]; float4 ww = w[q];
        s += v.x * ww.x + v.y * ww.y + v.z * ww.z + v.w * ww.w;
    }
    s += __shfl_down(s, 2, 4);
    s += __shfl_down(s, 1, 4);
    if (part == 0) t3[n] = s;
}

__global__ __launch_bounds__(256) void k_agg3(const float* __restrict__ t3,
                                              const int* __restrict__ cnt,
                                              const int* __restrict__ adjs,
                                              const float* __restrict__ adjw,
                                              const float* __restrict__ dinv,
                                              const float* __restrict__ b3,
                                              float* __restrict__ key) {
    int n = blockIdx.x * 256 + threadIdx.x;
    if (n >= NTOT) return;
    int m = cnt[n];
    if (m > CAP) m = CAP;
    float s = 0.f;
    for (int j = 0; j < m; j++)
        s += adjw[(size_t)n * CAP + j] * t3[adjs[(size_t)n * CAP + j]];
    float dv = dinv[n];
    s += dv * dv * t3[n];
    key[n] = tanhf(s + b3[0]);
}

// ---------------- stable top-60 per graph (exact argsort semantics) ----------------
__global__ __launch_bounds__(256) void k_select(const float* __restrict__ key,
                                                int* __restrict__ sel) {
    __shared__ float ks[NPG];
    int g = blockIdx.x, t = threadIdx.x;
    ks[t] = key[g * NPG + t];
    __syncthreads();
    float ki = ks[t];
    int rank = 0;
    for (int j = 0; j < NPG; j++) {
        float kj = ks[j];
        rank += (kj > ki) || (kj == ki && j < t);   // stable descending
    }
    if (rank < KTOP) sel[g * KTOP + rank] = g * NPG + t;
}

// ---------------- conv/MLP head: one block per graph (XCD-affine) ----------------
__global__ __launch_bounds__(256) void k_head(const float* __restrict__ X0,
                                              const float* __restrict__ X1,
                                              const float* __restrict__ X2,
                                              const float* __restrict__ key,
                                              const int* __restrict__ sel,
                                              const float* __restrict__ c1w,
                                              const float* __restrict__ c1b,
                                              const float* __restrict__ c2w,
                                              const float* __restrict__ c2b,
                                              const float* __restrict__ l1w,
                                              const float* __restrict__ l1b,
                                              const float* __restrict__ l2w,
                                              const float* __restrict__ l2b,
                                              float* __restrict__ out) {
    __shared__ __align__(16) float pch[KTOP * 132];   // pooled chunk, stride 132
    __shared__ __align__(16) float w1s[16 * 132];
    __shared__ int   seln[KTOP];
    __shared__ float selk[KTOP];
    __shared__ float c1s[16 * KTOP];
    __shared__ float mps[16 * 30];
    __shared__ float w2s[32 * 80];
    __shared__ float yb[832];
    __shared__ float l1p[256];
    __shared__ float l1v[128];

    int b = blockIdx.x, t = threadIdx.x;
    int g = ((b >> 3) << 3) | (b & 7);    // identity, but keeps graph->XCD g&7 explicit
    if (t < KTOP) {
        int nd = sel[g * KTOP + t];
        seln[t] = nd;
        selk[t] = key[nd];
    }

    float acc1[4] = {0.f, 0.f, 0.f, 0.f};
    for (int tc = 0; tc < 3; tc++) {
        const float* Xsrc = (tc == 0) ? X0 : ((tc == 1) ? X1 : X2);
        __syncthreads();
        for (int i = t; i < KTOP * 32; i += 256) {
            int k = i >> 5, q = i & 31;
            int nd = seln[k];
            *((float4*)&pch[k * 132 + q * 4]) = ((const float4*)Xsrc)[(size_t)nd * 32 + q];
        }
        for (int i = t; i < 16 * 128; i += 256) {
            int ch = i >> 7, tt = i & 127;
            w1s[ch * 132 + tt] = c1w[ch * TLDIM + tc * 128 + tt];
        }
        __syncthreads();
#pragma unroll
        for (int it = 0; it < 4; it++) {
            int e = it * 256 + t;
            if (e < 960) {                        // e = k*16 + ch
                int k = e >> 4, ch = e & 15;
                const float* pr = &pch[k * 132];
                const float* wr = &w1s[ch * 132];
                float s = 0.f;
#pragma unroll
                for (int q = 0; q < 32; q++) {
                    float4 pv = *((float4*)&pr[q * 4]);
                    float4 wv = *((float4*)&wr[q * 4]);
                    s += pv.x * wv.x + pv.y * wv.y + pv.z * wv.z + pv.w * wv.w;
                }
                acc1[it] += s;
            }
        }
    }
    __syncthreads();
#pragma unroll
    for (int it = 0; it < 4; it++) {
        int e = it * 256 + t;
        if (e < 960) {
            int k = e >> 4, ch = e & 15;
            float v = acc1[it] + selk[k] * c1w[ch * TLDIM + 384] + c1b[ch];
            c1s[ch * KTOP + k] = fmaxf(v, 0.f);
        }
    }
    for (int i = t; i < 2560; i += 256) w2s[i] = c2w[i];
    __syncthreads();
    for (int i = t; i < 480; i += 256) {
        int ch = i / 30, p = i - ch * 30;
        mps[ch * 30 + p] = fmaxf(c1s[ch * KTOP + 2 * p], c1s[ch * KTOP + 2 * p + 1]);
    }
    __syncthreads();
    for (int e = t; e < 832; e += 256) {
        int oc = e / 26, q = e - oc * 26;
        float s = 0.f;
#pragma unroll
        for (int ic = 0; ic < 16; ic++) {
            const float* mr = &mps[ic * 30 + q];
            const float* wr = &w2s[oc * 80 + ic * 5];
#pragma unroll
            for (int j = 0; j < 5; j++) s += mr[j] * wr[j];
        }
        yb[e] = fmaxf(s + c2b[oc], 0.f);
    }
    __syncthreads();
    {
        int u = t & 127, h = t >> 7;
        float s = 0.f;
        for (int d = h * 416; d < h * 416 + 416; d++) s += yb[d] * l1w[d * 128 + u];
        l1p[t] = s;
    }
    __syncthreads();
    if (t < 128) {
        float v = fmaxf(l1p[t] + l1p[t + 128] + l1b[t], 0.f);
        l1v[t] = v * l2w[t];
    }
    __syncthreads();
    if (t < 64) {
        float v = l1v[t] + l1v[t + 64];
        v += __shfl_down(v, 32);
        v += __shfl_down(v, 16);
        v += __shfl_down(v, 8);
        v += __shfl_down(v, 4);
        v += __shfl_down(v, 2);
        v += __shfl_down(v, 1);
        if (t == 0) out[g] = v + l2b[0];
    }
}

extern "C" void kernel_launch(void* const* d_in, const int* in_sizes, int n_in,
                              void* d_out, int out_size, void* d_ws, size_t ws_size,
                              hipStream_t stream) {
    (void)in_sizes; (void)n_in; (void)out_size; (void)ws_size;
    const float* zt  = (const float*)d_in[0];
    const float* W0  = (const float*)d_in[1];
    const float* b0  = (const float*)d_in[2];
    const float* W1  = (const float*)d_in[3];
    const float* b1  = (const float*)d_in[4];
    const float* W2  = (const float*)d_in[5];
    const float* b2  = (const float*)d_in[6];
    const float* W3  = (const float*)d_in[7];
    const float* b3  = (const float*)d_in[8];
    const float* c1w = (const float*)d_in[9];
    const float* c1b = (const float*)d_in[10];
    const float* c2w = (const float*)d_in[11];
    const float* c2b = (const float*)d_in[12];
    const float* l1w = (const float*)d_in[13];
    const float* l1b = (const float*)d_in[14];
    const float* l2w = (const float*)d_in[15];
    const float* l2b = (const float*)d_in[16];
    const float* ew  = (const float*)d_in[17];
    const int*   z   = (const int*)d_in[18];
    const int*   ei  = (const int*)d_in[19];
    float* out = (float*)d_out;

    char* wsp = (char*)d_ws;
    size_t off = 0;
    auto alloc = [&](size_t bytes) -> void* {
        void* p = wsp + off;
        off += (bytes + 255) & ~(size_t)255;
        return p;
    };
    float* deg  = (float*)alloc((size_t)NTOT * 4);            // becomes dinv after k_dinv
    int*   cnt  = (int*)  alloc((size_t)NTOT * 4);
    int*   adjs = (int*)  alloc((size_t)NTOT * CAP * 4);
    float* adjw = (float*)alloc((size_t)NTOT * CAP * 4);
    float* XA   = (float*)alloc((size_t)NTOT * HID * 4);      // emb, later X1
    float* XB   = (float*)alloc((size_t)NTOT * HID * 4);      // X0
    float* XC   = (float*)alloc((size_t)NTOT * HID * 4);      // X2
    float* t3   = (float*)alloc((size_t)NTOT * 4);
    float* keyb = (float*)alloc((size_t)NTOT * 4);
    int*   sel  = (int*)  alloc((size_t)BGR * KTOP * 4);

    dim3 b256(256);
    k_init   <<<NTOT / 256,      b256, 0, stream>>>(cnt);
    k_build  <<<EDG / 256,       b256, 0, stream>>>(ei, cnt, adjs);
    k_sortdeg<<<NTOT / 256,      b256, 0, stream>>>(ew, adjs, cnt, deg);
    k_dinv   <<<NTOT / 256,      b256, 0, stream>>>(deg);
    k_fin    <<<NTOT / 256,      b256, 0, stream>>>(ei, ew, deg, cnt, adjs, adjw);
    k_embed  <<<NTOT * 32 / 256, b256, 0, stream>>>(zt, z, XA);
    k_layer  <<<NTOT / 64,       b256, 0, stream>>>(XA, XB, cnt, adjs, adjw, deg, W0, b0); // X0
    k_layer  <<<NTOT / 64,       b256, 0, stream>>>(XB, XA, cnt, adjs, adjw, deg, W1, b1); // X1
    k_layer  <<<NTOT / 64,       b256, 0, stream>>>(XA, XC, cnt, adjs, adjw, deg, W2, b2); // X2
    k_dot3   <<<NTOT / 64,       b256, 0, stream>>>(XC, W3, t3);
    k_agg3   <<<NTOT / 256,      b256, 0, stream>>>(t3, cnt, adjs, adjw, deg, b3, keyb);
    k_select <<<BGR,             b256, 0, stream>>>(keyb, sel);
    k_head   <<<BGR,             b256, 0, stream>>>(XB, XA, XC, keyb, sel,
                                                    c1w, c1b, c2w, c2b,
                                                    l1w, l1b, l2w, l2b, out);
}

// Round 4
// 1086.780 us; speedup vs baseline: 4.5518x; 1.0539x over previous
//
#include <hip/hip_runtime.h>
#include <math.h>

#define NTOT   131072
#define NPG    256
#define BGR    512
#define HID    128
#define EDG    2097152
#define CAP    48          // max in-degree; round-1 validated (passed exact check)
#define KTOP   60
#define TLDIM  385

// ---------------- graph build ----------------
__global__ __launch_bounds__(256) void k_init(int* __restrict__ cnt) {
    int i = blockIdx.x * 256 + threadIdx.x;
    if (i < NTOT) cnt[i] = 0;
}

__global__ __launch_bounds__(256) void k_build(const int* __restrict__ ei,
                                               int* __restrict__ cnt,
                                               int* __restrict__ adjs) {
    int e = blockIdx.x * 256 + threadIdx.x;
    if (e >= EDG) return;
    int dst = ei[EDG + e];                 // edge_index[1][e]
    int pos = atomicAdd(&cnt[dst], 1);
    if (pos < CAP) adjs[(size_t)dst * CAP + pos] = e;
}

// sort each node's edge ids ascending (deterministic sum order), deg -> dinv
__global__ __launch_bounds__(256) void k_sortdeg(const float* __restrict__ ew,
                                                 int* __restrict__ adjs,
                                                 int* __restrict__ cnt,
                                                 float* __restrict__ dinv) {
    int n = blockIdx.x * 256 + threadIdx.x;
    if (n >= NTOT) return;
    int m = cnt[n];
    if (m > CAP) { m = CAP; cnt[n] = CAP; }
    int* a = adjs + (size_t)n * CAP;
    for (int i = 1; i < m; i++) {
        int key = a[i]; int j = i - 1;
        while (j >= 0 && a[j] > key) { a[j + 1] = a[j]; j--; }
        a[j + 1] = key;
    }
    float s = 0.f;
    for (int i = 0; i < m; i++) s += ew[a[i]];
    float deg = s + 1.0f;                   // self-loop weight appended last (ref order)
    dinv[n] = 1.0f / sqrtf(deg);            // same op sequence as round 3 (exact)
}

// rewrite adjacency: edge id -> (src, norm)
__global__ __launch_bounds__(256) void k_fin(const int* __restrict__ ei,
                                             const float* __restrict__ ew,
                                             const float* __restrict__ dinv,
                                             const int* __restrict__ cnt,
                                             int* __restrict__ adjs,
                                             float* __restrict__ adjw) {
    int n = blockIdx.x * 256 + threadIdx.x;
    if (n >= NTOT) return;
    int m = cnt[n];
    float dn = dinv[n];
    for (int i = 0; i < m; i++) {
        int e = adjs[(size_t)n * CAP + i];
        int s = ei[e];                       // edge_index[0][e]
        adjs[(size_t)n * CAP + i] = s;
        adjw[(size_t)n * CAP + i] = dinv[s] * ew[e] * dn;  // (dinv[src]*ew)*dinv[dst]
    }
}

// ---------------- embedding gather (XCD-affine: graph g -> XCD g&7) ----------------
__global__ __launch_bounds__(256) void k_embed(const float* __restrict__ zt,
                                               const int* __restrict__ z,
                                               float* __restrict__ X) {
    int b = blockIdx.x;
    int x = b & 7, i = b >> 3;
    int chunk = i & 31, gg = i >> 5;
    int graph = (gg << 3) | x;
    int nbase = graph * NPG + chunk * 8;
    int t = threadIdx.x;
    int n = nbase + (t >> 5), q = t & 31;
    int zi = z[n];
    ((float4*)X)[(size_t)n * 32 + q] = ((const float4*)zt)[(size_t)zi * 32 + q];
}

// ---------------- fused GCN layer v2 ----------------
// 128 nodes/block, 256 threads. Step 1: gather-aggregate into swizzled LDS.
// Step 2: 128x128(agg,LDS) @ 128x128(W,global/L2) with 8x8 register blocking.
// LDS layout: row stride 33 float4s; physical col4 = (logical k4 + row/8) & 31
//  -> step-2 strided-row b128 reads are 2-way (free) instead of 16-way.
__global__ __launch_bounds__(256) void k_layer(const float* __restrict__ Xin,
                                               float* __restrict__ Xout,
                                               const int* __restrict__ cnt,
                                               const int* __restrict__ adjs,
                                               const float* __restrict__ adjw,
                                               const float* __restrict__ dinv,
                                               const float* __restrict__ W,
                                               const float* __restrict__ bias) {
    __shared__ float4 agg4[128 * 33];              // 67.6 KB -> 2 blocks/CU
    int t = threadIdx.x;
    int b = blockIdx.x;                            // 1024 blocks
    int x = b & 7, i = b >> 3;
    int half = i & 1, gg = i >> 1;
    int graph = (gg << 3) | x;                     // graph -> XCD g&7 affinity
    int nbase = graph * NPG + half * 128;

    // ---- step 1: aggregate 128 rows (two 64-node passes; 4 thr/node, 32 ch) ----
    for (int h = 0; h < 2; h++) {
        int local = h * 64 + (t >> 2);             // row r in 0..127
        int node  = nbase + local;
        int p     = t & 3;                         // float4 indices 8p..8p+7
        float4 acc[8];
#pragma unroll
        for (int q = 0; q < 8; q++) acc[q] = make_float4(0.f, 0.f, 0.f, 0.f);
        int m = cnt[node];
        if (m > CAP) m = CAP;
        const int*   as = adjs + (size_t)node * CAP;
        const float* aw = adjw + (size_t)node * CAP;
#pragma unroll 2
        for (int j = 0; j < m; j++) {
            int s = as[j];
            float wgt = aw[j];
            const float4* r = ((const float4*)Xin) + (size_t)s * 32 + p * 8;
#pragma unroll
            for (int q = 0; q < 8; q++) {
                float4 v = r[q];
                acc[q].x += wgt * v.x; acc[q].y += wgt * v.y;
                acc[q].z += wgt * v.z; acc[q].w += wgt * v.w;
            }
        }
        float dv = dinv[node];
        float ws = dv * dv;                        // self-loop norm, added last (ref order)
        const float4* r = ((const float4*)Xin) + (size_t)node * 32 + p * 8;
#pragma unroll
        for (int q = 0; q < 8; q++) {
            float4 v = r[q];
            acc[q].x += ws * v.x; acc[q].y += ws * v.y;
            acc[q].z += ws * v.z; acc[q].w += ws * v.w;
        }
        int rot = local >> 3;
#pragma unroll
        for (int q = 0; q < 8; q++)
            agg4[local * 33 + ((8 * p + q + rot) & 31)] = acc[q];
    }
    __syncthreads();

    // ---- step 2: each thread 8 rows x 8 cols; k strictly ascending (exact) ----
    int rg = t & 15, cg = t >> 4;                  // rows rg*8..+7, cols cg*8..+7
    float a2[8][8];
#pragma unroll
    for (int i2 = 0; i2 < 8; i2++)
#pragma unroll
        for (int j = 0; j < 8; j++) a2[i2][j] = 0.f;

    int rowb = rg * 8;
    for (int kk4 = 0; kk4 < 32; kk4++) {
        float4 a4[8];
#pragma unroll
        for (int i2 = 0; i2 < 8; i2++)
            a4[i2] = agg4[(rowb + i2) * 33 + ((kk4 + rg) & 31)];
        float4 wv[8];                              // [kw][u]: cols cg*8+4u..+3
#pragma unroll
        for (int kw = 0; kw < 4; kw++) {
            const float4* wp = ((const float4*)(W + (size_t)(kk4 * 4 + kw) * HID)) + cg * 2;
            wv[kw * 2]     = wp[0];
            wv[kw * 2 + 1] = wp[1];
        }
#pragma unroll
        for (int kw = 0; kw < 4; kw++) {
#pragma unroll
            for (int i2 = 0; i2 < 8; i2++) {
                float a = (kw == 0) ? a4[i2].x : (kw == 1) ? a4[i2].y
                        : (kw == 2) ? a4[i2].z : a4[i2].w;
                a2[i2][0] += a * wv[kw * 2].x;
                a2[i2][1] += a * wv[kw * 2].y;
                a2[i2][2] += a * wv[kw * 2].z;
                a2[i2][3] += a * wv[kw * 2].w;
                a2[i2][4] += a * wv[kw * 2 + 1].x;
                a2[i2][5] += a * wv[kw * 2 + 1].y;
                a2[i2][6] += a * wv[kw * 2 + 1].z;
                a2[i2][7] += a * wv[kw * 2 + 1].w;
            }
        }
    }

    float4 bv0 = *(((const float4*)bias) + cg * 2);
    float4 bv1 = *(((const float4*)bias) + cg * 2 + 1);
#pragma unroll
    for (int i2 = 0; i2 < 8; i2++) {
        int row = nbase + rowb + i2;
        float4 o0, o1;
        o0.x = tanhf(a2[i2][0] + bv0.x); o0.y = tanhf(a2[i2][1] + bv0.y);
        o0.z = tanhf(a2[i2][2] + bv0.z); o0.w = tanhf(a2[i2][3] + bv0.w);
        o1.x = tanhf(a2[i2][4] + bv1.x); o1.y = tanhf(a2[i2][5] + bv1.y);
        o1.z = tanhf(a2[i2][6] + bv1.z); o1.w = tanhf(a2[i2][7] + bv1.w);
        float4* dst = (float4*)(Xout + (size_t)row * HID + cg * 8);
        dst[0] = o0;
        dst[1] = o1;
    }
}

// ---------------- layer 3 (128 -> 1): dot then scalar aggregation ----------------
__global__ __launch_bounds__(256) void k_dot3(const float* __restrict__ X2,
                                              const float* __restrict__ W3,
                                              float* __restrict__ t3) {
    int t = threadIdx.x;
    int n = blockIdx.x * 64 + (t >> 2);
    int part = t & 3;
    const float4* r = ((const float4*)X2) + (size_t)n * 32 + part * 8;
    const float4* w = ((const float4*)W3) + part * 8;
    float s = 0.f;
#pragma unroll
    for (int q = 0; q < 8; q++) {
        float4 v = r[q]; float4 ww = w[q];
        s += v.x * ww.x + v.y * ww.y + v.z * ww.z + v.w * ww.w;
    }
    s += __shfl_down(s, 2, 4);
    s += __shfl_down(s, 1, 4);
    if (part == 0) t3[n] = s;
}

__global__ __launch_bounds__(256) void k_agg3(const float* __restrict__ t3,
                                              const int* __restrict__ cnt,
                                              const int* __restrict__ adjs,
                                              const float* __restrict__ adjw,
                                              const float* __restrict__ dinv,
                                              const float* __restrict__ b3,
                                              float* __restrict__ key) {
    int n = blockIdx.x * 256 + threadIdx.x;
    if (n >= NTOT) return;
    int m = cnt[n];
    if (m > CAP) m = CAP;
    float s = 0.f;
    for (int j = 0; j < m; j++)
        s += adjw[(size_t)n * CAP + j] * t3[adjs[(size_t)n * CAP + j]];
    float dv = dinv[n];
    s += dv * dv * t3[n];
    key[n] = tanhf(s + b3[0]);
}

// ---------------- stable top-60 per graph (exact argsort semantics) ----------------
__global__ __launch_bounds__(256) void k_select(const float* __restrict__ key,
                                                int* __restrict__ sel) {
    __shared__ float ks[NPG];
    int g = blockIdx.x, t = threadIdx.x;
    ks[t] = key[g * NPG + t];
    __syncthreads();
    float ki = ks[t];
    int rank = 0;
    for (int j = 0; j < NPG; j++) {
        float kj = ks[j];
        rank += (kj > ki) || (kj == ki && j < t);   // stable descending
    }
    if (rank < KTOP) sel[g * KTOP + rank] = g * NPG + t;
}

// ---------------- conv/MLP head: one block per graph ----------------
__global__ __launch_bounds__(256) void k_head(const float* __restrict__ X0,
                                              const float* __restrict__ X1,
                                              const float* __restrict__ X2,
                                              const float* __restrict__ key,
                                              const int* __restrict__ sel,
                                              const float* __restrict__ c1w,
                                              const float* __restrict__ c1b,
                                              const float* __restrict__ c2w,
                                              const float* __restrict__ c2b,
                                              const float* __restrict__ l1w,
                                              const float* __restrict__ l1b,
                                              const float* __restrict__ l2w,
                                              const float* __restrict__ l2b,
                                              float* __restrict__ out) {
    __shared__ __align__(16) float pch[KTOP * 132];   // pooled chunk, stride 132
    __shared__ __align__(16) float w1s[16 * 132];
    __shared__ int   seln[KTOP];
    __shared__ float selk[KTOP];
    __shared__ float c1s[16 * KTOP];
    __shared__ float mps[16 * 30];
    __shared__ float w2s[32 * 80];
    __shared__ float yb[832];
    __shared__ float l1p[256];
    __shared__ float l1v[128];

    int g = blockIdx.x, t = threadIdx.x;
    if (t < KTOP) {
        int nd = sel[g * KTOP + t];
        seln[t] = nd;
        selk[t] = key[nd];
    }

    float acc1[4] = {0.f, 0.f, 0.f, 0.f};
    for (int tc = 0; tc < 3; tc++) {
        const float* Xsrc = (tc == 0) ? X0 : ((tc == 1) ? X1 : X2);
        __syncthreads();
        for (int i = t; i < KTOP * 32; i += 256) {
            int k = i >> 5, q = i & 31;
            int nd = seln[k];
            *((float4*)&pch[k * 132 + q * 4]) = ((const float4*)Xsrc)[(size_t)nd * 32 + q];
        }
        for (int i = t; i < 16 * 128; i += 256) {
            int ch = i >> 7, tt = i & 127;
            w1s[ch * 132 + tt] = c1w[ch * TLDIM + tc * 128 + tt];
        }
        __syncthreads();
#pragma unroll
        for (int it = 0; it < 4; it++) {
            int e = it * 256 + t;
            if (e < 960) {                        // e = k*16 + ch
                int k = e >> 4, ch = e & 15;
                const float* pr = &pch[k * 132];
                const float* wr = &w1s[ch * 132];
                float s = 0.f;
#pragma unroll
                for (int q = 0; q < 32; q++) {
                    float4 pv = *((float4*)&pr[q * 4]);
                    float4 wv = *((float4*)&wr[q * 4]);
                    s += pv.x * wv.x + pv.y * wv.y + pv.z * wv.z + pv.w * wv.w;
                }
                acc1[it] += s;
            }
        }
    }
    __syncthreads();
#pragma unroll
    for (int it = 0; it < 4; it++) {
        int e = it * 256 + t;
        if (e < 960) {
            int k = e >> 4, ch = e & 15;
            float v = acc1[it] + selk[k] * c1w[ch * TLDIM + 384] + c1b[ch];
            c1s[ch * KTOP + k] = fmaxf(v, 0.f);
        }
    }
    for (int i = t; i < 2560; i += 256) w2s[i] = c2w[i];
    __syncthreads();
    for (int i = t; i < 480; i += 256) {
        int ch = i / 30, p = i - ch * 30;
        mps[ch * 30 + p] = fmaxf(c1s[ch * KTOP + 2 * p], c1s[ch * KTOP + 2 * p + 1]);
    }
    __syncthreads();
    for (int e = t; e < 832; e += 256) {
        int oc = e / 26, q = e - oc * 26;
        float s = 0.f;
#pragma unroll
        for (int ic = 0; ic < 16; ic++) {
            const float* mr = &mps[ic * 30 + q];
            const float* wr = &w2s[oc * 80 + ic * 5];
#pragma unroll
            for (int j = 0; j < 5; j++) s += mr[j] * wr[j];
        }
        yb[e] = fmaxf(s + c2b[oc], 0.f);
    }
    __syncthreads();
    {
        int u = t & 127, h = t >> 7;
        float s = 0.f;
        for (int d = h * 416; d < h * 416 + 416; d++) s += yb[d] * l1w[d * 128 + u];
        l1p[t] = s;
    }
    __syncthreads();
    if (t < 128) {
        float v = fmaxf(l1p[t] + l1p[t + 128] + l1b[t], 0.f);
        l1v[t] = v * l2w[t];
    }
    __syncthreads();
    if (t < 64) {
        float v = l1v[t] + l1v[t + 64];
        v += __shfl_down(v, 32);
        v += __shfl_down(v, 16);
        v += __shfl_down(v, 8);
        v += __shfl_down(v, 4);
        v += __shfl_down(v, 2);
        v += __shfl_down(v, 1);
        if (t == 0) out[g] = v + l2b[0];
    }
}

extern "C" void kernel_launch(void* const* d_in, const int* in_sizes, int n_in,
                              void* d_out, int out_size, void* d_ws, size_t ws_size,
                              hipStream_t stream) {
    (void)in_sizes; (void)n_in; (void)out_size; (void)ws_size;
    const float* zt  = (const float*)d_in[0];
    const float* W0  = (const float*)d_in[1];
    const float* b0  = (const float*)d_in[2];
    const float* W1  = (const float*)d_in[3];
    const float* b1  = (const float*)d_in[4];
    const float* W2  = (const float*)d_in[5];
    const float* b2  = (const float*)d_in[6];
    const float* W3  = (const float*)d_in[7];
    const float* b3  = (const float*)d_in[8];
    const float* c1w = (const float*)d_in[9];
    const float* c1b = (const float*)d_in[10];
    const float* c2w = (const float*)d_in[11];
    const float* c2b = (const float*)d_in[12];
    const float* l1w = (const float*)d_in[13];
    const float* l1b = (const float*)d_in[14];
    const float* l2w = (const float*)d_in[15];
    const float* l2b = (const float*)d_in[16];
    const float* ew  = (const float*)d_in[17];
    const int*   z   = (const int*)d_in[18];
    const int*   ei  = (const int*)d_in[19];
    float* out = (float*)d_out;

    char* wsp = (char*)d_ws;
    size_t off = 0;
    auto alloc = [&](size_t bytes) -> void* {
        void* p = wsp + off;
        off += (bytes + 255) & ~(size_t)255;
        return p;
    };
    float* dinv = (float*)alloc((size_t)NTOT * 4);
    int*   cnt  = (int*)  alloc((size_t)NTOT * 4);
    int*   adjs = (int*)  alloc((size_t)NTOT * CAP * 4);
    float* adjw = (float*)alloc((size_t)NTOT * CAP * 4);
    float* XA   = (float*)alloc((size_t)NTOT * HID * 4);      // emb, later X1
    float* XB   = (float*)alloc((size_t)NTOT * HID * 4);      // X0
    float* XC   = (float*)alloc((size_t)NTOT * HID * 4);      // X2
    float* t3   = (float*)alloc((size_t)NTOT * 4);
    float* keyb = (float*)alloc((size_t)NTOT * 4);
    int*   sel  = (int*)  alloc((size_t)BGR * KTOP * 4);

    dim3 b256(256);
    k_init   <<<NTOT / 256,      b256, 0, stream>>>(cnt);
    k_build  <<<EDG / 256,       b256, 0, stream>>>(ei, cnt, adjs);
    k_sortdeg<<<NTOT / 256,      b256, 0, stream>>>(ew, adjs, cnt, dinv);
    k_fin    <<<NTOT / 256,      b256, 0, stream>>>(ei, ew, dinv, cnt, adjs, adjw);
    k_embed  <<<NTOT * 32 / 256, b256, 0, stream>>>(zt, z, XA);
    k_layer  <<<NTOT / 128,      b256, 0, stream>>>(XA, XB, cnt, adjs, adjw, dinv, W0, b0); // X0
    k_layer  <<<NTOT / 128,      b256, 0, stream>>>(XB, XA, cnt, adjs, adjw, dinv, W1, b1); // X1
    k_layer  <<<NTOT / 128,      b256, 0, stream>>>(XA, XC, cnt, adjs, adjw, dinv, W2, b2); // X2
    k_dot3   <<<NTOT / 64,       b256, 0, stream>>>(XC, W3, t3);
    k_agg3   <<<NTOT / 256,      b256, 0, stream>>>(t3, cnt, adjs, adjw, dinv, b3, keyb);
    k_select <<<BGR,             b256, 0, stream>>>(keyb, sel);
    k_head   <<<BGR,             b256, 0, stream>>>(XB, XA, XC, keyb, sel,
                                                    c1w, c1b, c2w, c2b,
                                                    l1w, l1b, l2w, l2b, out);
}

// Round 5
// 790.638 us; speedup vs baseline: 6.2567x; 1.3746x over previous
//
#include <hip/hip_runtime.h>
#include <math.h>

#define NTOT   131072
#define NPG    256
#define BGR    512
#define HID    128
#define EDG    2097152
#define EPG    4096       // edges per graph (contiguous slice [g*4096,(g+1)*4096))
#define KTOP   60
#define TLDIM  385

// X (gather) layout: float4 c4 -> phys within 32-float4 row
__device__ __forceinline__ int physX(int row, int c4) {
    return (c4 + row + (row >> 3)) & 31;
}
// AGG (GEMM) layout
__device__ __forceinline__ int physA(int row, int c4) {
    return (c4 + (row >> 3) + ((row & 1) << 2)) & 31;
}

// ================= mega kernel: build + embed + 3 GCN layers + key + top-60 ===============
__global__ __launch_bounds__(512, 2) void k_gnn(
        const float* __restrict__ zt, const int* __restrict__ z,
        const int* __restrict__ ei, const float* __restrict__ ew,
        const float* __restrict__ W0, const float* __restrict__ b0,
        const float* __restrict__ W1, const float* __restrict__ b1,
        const float* __restrict__ W2, const float* __restrict__ b2,
        const float* __restrict__ W3, const float* __restrict__ b3,
        float* __restrict__ X0, float* __restrict__ X1, float* __restrict__ X2,
        float* __restrict__ keyb, int* __restrict__ sel) {
    __shared__ float4 XS[NPG * 32];              // 128 KB; aliased as build scratch first
    __shared__ float  wnL[EPG];                  // 16 KB  normalized edge weights (CSR slots)
    __shared__ unsigned char esrcL[EPG];         // 4 KB   local src per slot
    __shared__ unsigned short offL[NPG + 2];     // CSR offsets (exclusive)
    __shared__ float  selfnL[NPG];               // dinv^2
    __shared__ float  dinvL[NPG];
    __shared__ float  t3s[NPG];
    __shared__ float  keyL[NPG];
    __shared__ int    cntL[NPG];                 // counts -> scan -> reused as z cache

    int t = threadIdx.x;
    int g = blockIdx.x;

    // ---- build scratch aliases inside XS (dead once XS staged) ----
    float*         ewL  = (float*)XS;                              // [0,16K)
    unsigned char* srcB = (unsigned char*)XS + 16384;              // [16K,20K)
    unsigned int*  dstW = (unsigned int*)((char*)XS + 20480);      // [20K,24K) as 1024 words
    short*         eidL = (short*)((char*)XS + 24576);             // [24K,32K)

    if (t < NPG) cntL[t] = 0;
    __syncthreads();
    // stage the graph's edges (coalesced) + count in-degrees (order-free)
    for (int j = t; j < EPG; j += 512) {
        int e  = g * EPG + j;
        int sN = ei[e] & (NPG - 1);          // src local (graphs are 256-aligned)
        int dN = ei[EDG + e] & (NPG - 1);    // dst local
        ewL[j] = ew[e];
        srcB[j] = (unsigned char)sN;
        ((unsigned char*)dstW)[j] = (unsigned char)dN;
        atomicAdd(&cntL[dN], 1);
    }
    __syncthreads();
    // inclusive scan of cntL (Hillis-Steele, in place)
    for (int s = 1; s < NPG; s <<= 1) {
        int v = 0;
        if (t < NPG && t >= s) v = cntL[t - s];
        __syncthreads();
        if (t < NPG) cntL[t] += v;
        __syncthreads();
    }
    if (t == 0) offL[0] = 0;
    if (t < NPG) offL[t + 1] = (unsigned short)cntL[t];
    __syncthreads();
    // deterministic fill: thread n scans all edges in e-ASCENDING order via LDS
    // broadcast reads; collects its in-edges + deg sum in exactly the round-4 order.
    if (t < NPG) {
        int cur = offL[t];
        float s = 0.f;
        for (int w = 0; w < EPG / 4; w++) {
            unsigned int word = dstW[w];               // same addr all lanes: broadcast
#pragma unroll
            for (int bb = 0; bb < 4; bb++) {
                if (((word >> (8 * bb)) & 255u) == (unsigned int)t) {
                    int e = w * 4 + bb;
                    eidL[cur++] = (short)e;
                    s += ewL[e];                       // e-ascending (== sorted order)
                }
            }
        }
        float dv = 1.0f / sqrtf(s + 1.0f);             // self-loop last, same as r4
        dinvL[t]  = dv;
        selfnL[t] = dv * dv;
    }
    __syncthreads();
    // normalize slots -> (esrcL, wnL); stage z into cntL (counts now dead)
    if (t < NPG) {
        int o = offL[t], m2 = offL[t + 1] - o;
        float dn = dinvL[t];
        for (int i = 0; i < m2; i++) {
            int e  = eidL[o + i];
            int sN = srcB[e];
            esrcL[o + i] = (unsigned char)sN;
            wnL[o + i]   = dinvL[sN] * ewL[e] * dn;    // same expr as r4 k_fin
        }
        cntL[t] = z[g * NPG + t];
    }
    __syncthreads();
    // ---- stage X = zt[z[n]] into XS (gather layout); overwrites build scratch ----
    for (int i = t; i < NPG * 32; i += 512) {
        int row = i >> 5, c4 = i & 31;
        int zi = cntL[row];
        XS[row * 32 + physX(row, c4)] = ((const float4*)zt)[(size_t)zi * 32 + c4];
    }
    __syncthreads();

    // ================= 3 GCN layers =================
#pragma unroll 1
    for (int layer = 0; layer < 3; layer++) {
        const float* W    = (layer == 0) ? W0 : (layer == 1) ? W1 : W2;
        const float* bias = (layer == 0) ? b0 : (layer == 1) ? b1 : b2;
        float* Xout       = (layer == 0) ? X0 : (layer == 1) ? X1 : X2;

        // ---- gather: 2 threads/node, 64 channels each, acc in 64 VGPRs ----
        int n = t >> 1, h = t & 1;
        int cb = h * 16;
        float4 acc[16];
#pragma unroll
        for (int q = 0; q < 16; q++) acc[q] = make_float4(0.f, 0.f, 0.f, 0.f);
        {
            int o = offL[n], m2 = offL[n + 1] - o;
            for (int i = 0; i < m2; i++) {
                int sN = esrcL[o + i];
                float wgt = wnL[o + i];
                const float4* rb = XS + sN * 32;
#pragma unroll
                for (int q = 0; q < 16; q++) {
                    float4 v = rb[physX(sN, cb + q)];
                    acc[q].x += wgt * v.x; acc[q].y += wgt * v.y;
                    acc[q].z += wgt * v.z; acc[q].w += wgt * v.w;
                }
            }
            float ws = selfnL[n];                       // self-loop LAST (r4 order)
            const float4* rb = XS + n * 32;
#pragma unroll
            for (int q = 0; q < 16; q++) {
                float4 v = rb[physX(n, cb + q)];
                acc[q].x += ws * v.x; acc[q].y += ws * v.y;
                acc[q].z += ws * v.z; acc[q].w += ws * v.w;
            }
        }
        __syncthreads();                                // all X reads done
        // write AGG (GEMM layout) over the X region
#pragma unroll
        for (int q = 0; q < 16; q++)
            XS[n * 32 + physA(n, cb + q)] = acc[q];
        __syncthreads();

        // ---- GEMM 256x128 @ 128x128, k strictly ascending (exact r4 chains) ----
        int rg = t & 31, cg = t >> 5;                   // rows rg*8..+7, cols cg*8..+7
        float a2[8][8];
#pragma unroll
        for (int i = 0; i < 8; i++)
#pragma unroll
            for (int j = 0; j < 8; j++) a2[i][j] = 0.f;
        for (int k4 = 0; k4 < 32; k4++) {
            float4 a4[8];
#pragma unroll
            for (int i = 0; i < 8; i++)
                a4[i] = XS[(rg * 8 + i) * 32 + physA(rg * 8 + i, k4)];
            float4 wv[8];
#pragma unroll
            for (int kw = 0; kw < 4; kw++) {
                const float4* wp = ((const float4*)(W + (size_t)(k4 * 4 + kw) * HID)) + cg * 2;
                wv[kw * 2]     = wp[0];
                wv[kw * 2 + 1] = wp[1];
            }
#pragma unroll
            for (int kw = 0; kw < 4; kw++) {
#pragma unroll
                for (int i = 0; i < 8; i++) {
                    float a = (kw == 0) ? a4[i].x : (kw == 1) ? a4[i].y
                            : (kw == 2) ? a4[i].z : a4[i].w;
                    a2[i][0] += a * wv[kw * 2].x;     a2[i][1] += a * wv[kw * 2].y;
                    a2[i][2] += a * wv[kw * 2].z;     a2[i][3] += a * wv[kw * 2].w;
                    a2[i][4] += a * wv[kw * 2 + 1].x; a2[i][5] += a * wv[kw * 2 + 1].y;
                    a2[i][6] += a * wv[kw * 2 + 1].z; a2[i][7] += a * wv[kw * 2 + 1].w;
                }
            }
        }
        float4 bv0 = *(((const float4*)bias) + cg * 2);
        float4 bv1 = *(((const float4*)bias) + cg * 2 + 1);
        float4 o0[8], o1[8];
#pragma unroll
        for (int i = 0; i < 8; i++) {
            o0[i].x = tanhf(a2[i][0] + bv0.x); o0[i].y = tanhf(a2[i][1] + bv0.y);
            o0[i].z = tanhf(a2[i][2] + bv0.z); o0[i].w = tanhf(a2[i][3] + bv0.w);
            o1[i].x = tanhf(a2[i][4] + bv1.x); o1[i].y = tanhf(a2[i][5] + bv1.y);
            o1[i].z = tanhf(a2[i][6] + bv1.z); o1[i].w = tanhf(a2[i][7] + bv1.w);
        }
        __syncthreads();                                // AGG fully consumed
#pragma unroll
        for (int i = 0; i < 8; i++) {
            int rl = rg * 8 + i;
            XS[rl * 32 + physX(rl, cg * 2)]     = o0[i];
            XS[rl * 32 + physX(rl, cg * 2 + 1)] = o1[i];
        }
        __syncthreads();
        // coalesced copy-out XS -> Xout (global)
        for (int i = t; i < NPG * 32; i += 512) {
            int row = i >> 5, c4 = i & 31;
            ((float4*)Xout)[(size_t)g * NPG * 32 + i] = XS[row * 32 + physX(row, c4)];
        }
        // no sync needed: next phase only READS XS
    }

    // ---- layer 3 scalar: t3 = X2-row . W3 with r4's exact 4-part structure ----
    {
        int n = t >> 1, h = t & 1;
        const float4* w4 = (const float4*)W3;
        const float4* rb = XS + n * 32;
        float a = 0.f, b = 0.f;
#pragma unroll
        for (int q = 0; q < 8; q++) {
            float4 v = rb[physX(n, h * 8 + q)];
            float4 ww = w4[h * 8 + q];
            a += v.x * ww.x + v.y * ww.y + v.z * ww.z + v.w * ww.w;   // part p_h
        }
#pragma unroll
        for (int q = 0; q < 8; q++) {
            float4 v = rb[physX(n, (h + 2) * 8 + q)];
            float4 ww = w4[(h + 2) * 8 + q];
            b += v.x * ww.x + v.y * ww.y + v.z * ww.z + v.w * ww.w;   // part p_{h+2}
        }
        float s = a + b;                                // == r4 shfl_down(2,4) step
        float so = __shfl_down(s, 1);                   // pair lanes 2n,2n+1
        if (h == 0) t3s[n] = s + so;                    // == r4 shfl_down(1,4) step
    }
    __syncthreads();

    // ---- key = tanh(agg(t3) + b3), then stable top-60 rank ----
    if (t < NPG) {
        int o = offL[t], m2 = offL[t + 1] - o;
        float s = 0.f;
        for (int i = 0; i < m2; i++)
            s += wnL[o + i] * t3s[esrcL[o + i]];
        s += selfnL[t] * t3s[t];
        float key = tanhf(s + b3[0]);
        keyL[t] = key;
        keyb[g * NPG + t] = key;
    }
    __syncthreads();
    if (t < NPG) {
        float ki = keyL[t];
        int rank = 0;
        for (int j = 0; j < NPG; j++) {
            float kj = keyL[j];
            rank += (kj > ki) || (kj == ki && j < t);
        }
        if (rank < KTOP) sel[g * KTOP + rank] = g * NPG + t;
    }
}

// ---------------- conv/MLP head: one block per graph (unchanged from r4) ----------------
__global__ __launch_bounds__(256) void k_head(const float* __restrict__ X0,
                                              const float* __restrict__ X1,
                                              const float* __restrict__ X2,
                                              const float* __restrict__ key,
                                              const int* __restrict__ sel,
                                              const float* __restrict__ c1w,
                                              const float* __restrict__ c1b,
                                              const float* __restrict__ c2w,
                                              const float* __restrict__ c2b,
                                              const float* __restrict__ l1w,
                                              const float* __restrict__ l1b,
                                              const float* __restrict__ l2w,
                                              const float* __restrict__ l2b,
                                              float* __restrict__ out) {
    __shared__ __align__(16) float pch[KTOP * 132];
    __shared__ __align__(16) float w1s[16 * 132];
    __shared__ int   seln[KTOP];
    __shared__ float selk[KTOP];
    __shared__ float c1s[16 * KTOP];
    __shared__ float mps[16 * 30];
    __shared__ float w2s[32 * 80];
    __shared__ float yb[832];
    __shared__ float l1p[256];
    __shared__ float l1v[128];

    int g = blockIdx.x, t = threadIdx.x;
    if (t < KTOP) {
        int nd = sel[g * KTOP + t];
        seln[t] = nd;
        selk[t] = key[nd];
    }

    float acc1[4] = {0.f, 0.f, 0.f, 0.f};
    for (int tc = 0; tc < 3; tc++) {
        const float* Xsrc = (tc == 0) ? X0 : ((tc == 1) ? X1 : X2);
        __syncthreads();
        for (int i = t; i < KTOP * 32; i += 256) {
            int k = i >> 5, q = i & 31;
            int nd = seln[k];
            *((float4*)&pch[k * 132 + q * 4]) = ((const float4*)Xsrc)[(size_t)nd * 32 + q];
        }
        for (int i = t; i < 16 * 128; i += 256) {
            int ch = i >> 7, tt = i & 127;
            w1s[ch * 132 + tt] = c1w[ch * TLDIM + tc * 128 + tt];
        }
        __syncthreads();
#pragma unroll
        for (int it = 0; it < 4; it++) {
            int e = it * 256 + t;
            if (e < 960) {
                int k = e >> 4, ch = e & 15;
                const float* pr = &pch[k * 132];
                const float* wr = &w1s[ch * 132];
                float s = 0.f;
#pragma unroll
                for (int q = 0; q < 32; q++) {
                    float4 pv = *((float4*)&pr[q * 4]);
                    float4 wv = *((float4*)&wr[q * 4]);
                    s += pv.x * wv.x + pv.y * wv.y + pv.z * wv.z + pv.w * wv.w;
                }
                acc1[it] += s;
            }
        }
    }
    __syncthreads();
#pragma unroll
    for (int it = 0; it < 4; it++) {
        int e = it * 256 + t;
        if (e < 960) {
            int k = e >> 4, ch = e & 15;
            float v = acc1[it] + selk[k] * c1w[ch * TLDIM + 384] + c1b[ch];
            c1s[ch * KTOP + k] = fmaxf(v, 0.f);
        }
    }
    for (int i = t; i < 2560; i += 256) w2s[i] = c2w[i];
    __syncthreads();
    for (int i = t; i < 480; i += 256) {
        int ch = i / 30, p = i - ch * 30;
        mps[ch * 30 + p] = fmaxf(c1s[ch * KTOP + 2 * p], c1s[ch * KTOP + 2 * p + 1]);
    }
    __syncthreads();
    for (int e = t; e < 832; e += 256) {
        int oc = e / 26, q = e - oc * 26;
        float s = 0.f;
#pragma unroll
        for (int ic = 0; ic < 16; ic++) {
            const float* mr = &mps[ic * 30 + q];
            const float* wr = &w2s[oc * 80 + ic * 5];
#pragma unroll
            for (int j = 0; j < 5; j++) s += mr[j] * wr[j];
        }
        yb[e] = fmaxf(s + c2b[oc], 0.f);
    }
    __syncthreads();
    {
        int u = t & 127, h = t >> 7;
        float s = 0.f;
        for (int d = h * 416; d < h * 416 + 416; d++) s += yb[d] * l1w[d * 128 + u];
        l1p[t] = s;
    }
    __syncthreads();
    if (t < 128) {
        float v = fmaxf(l1p[t] + l1p[t + 128] + l1b[t], 0.f);
        l1v[t] = v * l2w[t];
    }
    __syncthreads();
    if (t < 64) {
        float v = l1v[t] + l1v[t + 64];
        v += __shfl_down(v, 32);
        v += __shfl_down(v, 16);
        v += __shfl_down(v, 8);
        v += __shfl_down(v, 4);
        v += __shfl_down(v, 2);
        v += __shfl_down(v, 1);
        if (t == 0) out[g] = v + l2b[0];
    }
}

extern "C" void kernel_launch(void* const* d_in, const int* in_sizes, int n_in,
                              void* d_out, int out_size, void* d_ws, size_t ws_size,
                              hipStream_t stream) {
    (void)in_sizes; (void)n_in; (void)out_size; (void)ws_size;
    const float* zt  = (const float*)d_in[0];
    const float* W0  = (const float*)d_in[1];
    const float* b0  = (const float*)d_in[2];
    const float* W1  = (const float*)d_in[3];
    const float* b1  = (const float*)d_in[4];
    const float* W2  = (const float*)d_in[5];
    const float* b2  = (const float*)d_in[6];
    const float* W3  = (const float*)d_in[7];
    const float* b3  = (const float*)d_in[8];
    const float* c1w = (const float*)d_in[9];
    const float* c1b = (const float*)d_in[10];
    const float* c2w = (const float*)d_in[11];
    const float* c2b = (const float*)d_in[12];
    const float* l1w = (const float*)d_in[13];
    const float* l1b = (const float*)d_in[14];
    const float* l2w = (const float*)d_in[15];
    const float* l2b = (const float*)d_in[16];
    const float* ew  = (const float*)d_in[17];
    const int*   z   = (const int*)d_in[18];
    const int*   ei  = (const int*)d_in[19];
    float* out = (float*)d_out;

    char* wsp = (char*)d_ws;
    size_t off = 0;
    auto alloc = [&](size_t bytes) -> void* {
        void* p = wsp + off;
        off += (bytes + 255) & ~(size_t)255;
        return p;
    };
    float* X0   = (float*)alloc((size_t)NTOT * HID * 4);
    float* X1   = (float*)alloc((size_t)NTOT * HID * 4);
    float* X2   = (float*)alloc((size_t)NTOT * HID * 4);
    float* keyb = (float*)alloc((size_t)NTOT * 4);
    int*   sel  = (int*)  alloc((size_t)BGR * KTOP * 4);

    k_gnn <<<BGR, dim3(512), 0, stream>>>(zt, z, ei, ew,
                                          W0, b0, W1, b1, W2, b2, W3, b3,
                                          X0, X1, X2, keyb, sel);
    k_head<<<BGR, dim3(256), 0, stream>>>(X0, X1, X2, keyb, sel,
                                          c1w, c1b, c2w, c2b,
                                          l1w, l1b, l2w, l2b, out);
}

// Round 6
// 778.063 us; speedup vs baseline: 6.3578x; 1.0162x over previous
//
#include <hip/hip_runtime.h>
#include <math.h>

#define NTOT   131072
#define NPG    256
#define BGR    512
#define HID    128
#define EDG    2097152
#define EPG    4096       // edges per graph (contiguous slice [g*4096,(g+1)*4096))
#define EPGP   4864       // padded CSR capacity: 4096 + 3*256
#define KTOP   60
#define TLDIM  385

// X (gather) layout: float4 c4 -> phys within 32-float4 row
__device__ __forceinline__ int physX(int row, int c4) {
    return (c4 + row + (row >> 3)) & 31;
}
// AGG (GEMM) layout
__device__ __forceinline__ int physA(int row, int c4) {
    return (c4 + (row >> 3) + ((row & 1) << 2)) & 31;
}

// ================= mega kernel: build + embed + 3 GCN layers + key + top-60 ===============
__global__ __launch_bounds__(512, 2) void k_gnn(
        const float* __restrict__ zt, const int* __restrict__ z,
        const int* __restrict__ ei, const float* __restrict__ ew,
        const float* __restrict__ W0, const float* __restrict__ b0,
        const float* __restrict__ W1, const float* __restrict__ b1,
        const float* __restrict__ W2, const float* __restrict__ b2,
        const float* __restrict__ W3, const float* __restrict__ b3,
        float* __restrict__ X0, float* __restrict__ X1, float* __restrict__ X2,
        float* __restrict__ keyb, int* __restrict__ sel) {
    __shared__ float4 XS[NPG * 32];              // 128 KB; aliased as build scratch first
    __shared__ float  wnL[EPGP];                 // 19 KB  normalized edge weights (padded CSR)
    __shared__ __align__(4) unsigned char esrcL[EPGP];  // 4.75 KB local src per slot
    __shared__ unsigned short offL[NPG + 1];     // padded CSR offsets (4-aligned)
    __shared__ unsigned short mLn[NPG];          // true in-degree per node
    __shared__ float  selfnL[NPG];               // dinv^2
    __shared__ float  dinvL[NPG];
    __shared__ float  t3s[NPG];
    __shared__ float  keyL[NPG];
    __shared__ int    cntL[NPG];                 // counts -> scan -> reused as z cache

    int t = threadIdx.x;
    int g = blockIdx.x;

    // ---- build scratch aliases inside XS (dead once XS staged) ----
    float*         ewL  = (float*)XS;                              // [0,16K)
    unsigned char* srcB = (unsigned char*)XS + 16384;              // [16K,20K)
    unsigned int*  dstW = (unsigned int*)((char*)XS + 20480);      // [20K,24K) as 1024 words
    short*         eidL = (short*)((char*)XS + 24576);             // [24K,33.75K)

    if (t < NPG) cntL[t] = 0;
    __syncthreads();
    // stage the graph's edges (coalesced) + count in-degrees (order-free)
    for (int j = t; j < EPG; j += 512) {
        int e  = g * EPG + j;
        int sN = ei[e] & (NPG - 1);          // src local (graphs are 256-aligned)
        int dN = ei[EDG + e] & (NPG - 1);    // dst local
        ewL[j] = ew[e];
        srcB[j] = (unsigned char)sN;
        ((unsigned char*)dstW)[j] = (unsigned char)dN;
        atomicAdd(&cntL[dN], 1);
    }
    __syncthreads();
    if (t < NPG) {
        mLn[t] = (unsigned short)cntL[t];
        cntL[t] = (cntL[t] + 3) & ~3;        // pad to multiple of 4
    }
    __syncthreads();
    // inclusive scan of padded counts (Hillis-Steele, in place)
    for (int s = 1; s < NPG; s <<= 1) {
        int v = 0;
        if (t < NPG && t >= s) v = cntL[t - s];
        __syncthreads();
        if (t < NPG) cntL[t] += v;
        __syncthreads();
    }
    if (t == 0) offL[0] = 0;
    if (t < NPG) offL[t + 1] = (unsigned short)cntL[t];
    __syncthreads();
    // deterministic fill: thread n scans all edges in e-ASCENDING order via LDS
    // broadcast reads; collects its in-edges + deg sum (round-5 order, exact).
    if (t < NPG) {
        int cur = offL[t];
        float s = 0.f;
        for (int w = 0; w < EPG / 4; w++) {
            unsigned int word = dstW[w];               // same addr all lanes: broadcast
#pragma unroll
            for (int bb = 0; bb < 4; bb++) {
                if (((word >> (8 * bb)) & 255u) == (unsigned int)t) {
                    int e = w * 4 + bb;
                    eidL[cur++] = (short)e;
                    s += ewL[e];                       // e-ascending (== sorted order)
                }
            }
        }
        float dv = 1.0f / sqrtf(s + 1.0f);             // self-loop last, same as r5
        dinvL[t]  = dv;
        selfnL[t] = dv * dv;
    }
    __syncthreads();
    // normalize slots -> (esrcL, wnL); pad tail with exact no-ops; stage z
    if (t < NPG) {
        int o = offL[t], m = mLn[t], pc = offL[t + 1] - o;
        float dn = dinvL[t];
        for (int i = 0; i < m; i++) {
            int e  = eidL[o + i];
            int sN = srcB[e];
            esrcL[o + i] = (unsigned char)sN;
            wnL[o + i]   = dinvL[sN] * ewL[e] * dn;    // same expr as r5
        }
        for (int i = m; i < pc; i++) {                 // w=0 * own row: bit-exact no-op
            esrcL[o + i] = (unsigned char)t;
            wnL[o + i]   = 0.f;
        }
        cntL[t] = z[g * NPG + t];
    }
    __syncthreads();
    // ---- stage X = zt[z[n]] into XS (gather layout); overwrites build scratch ----
    for (int i = t; i < NPG * 32; i += 512) {
        int row = i >> 5, c4 = i & 31;
        int zi = cntL[row];
        XS[row * 32 + physX(row, c4)] = ((const float4*)zt)[(size_t)zi * 32 + c4];
    }
    __syncthreads();

    const unsigned int* esrcW = (const unsigned int*)esrcL;
    const float4*       wn4   = (const float4*)wnL;
    int wid  = t >> 6;                               // wave 0..7
    int l    = t & 63;
    int half = l >> 5;
    int c4   = l & 31;

    // ================= 3 GCN layers =================
#pragma unroll 1
    for (int layer = 0; layer < 3; layer++) {
        const float* W    = (layer == 0) ? W0 : (layer == 1) ? W1 : W2;
        const float* bias = (layer == 0) ? b0 : (layer == 1) ? b1 : b2;
        float* Xout       = (layer == 0) ? X0 : (layer == 1) ? X1 : X2;

        // ---- gather: half-wave per node, ROW-BROADCAST reads (conflict-free) ----
        float4 accA[16];
#pragma unroll
        for (int it = 0; it < 16; it++) {
            int p    = wid * 16 + it;                // pair 0..127
            int node = 2 * p + half;
            int oA = offL[2 * p], oM = offL[2 * p + 1], oE = offL[2 * p + 2];
            int m4A = (oM - oA) >> 2, m4B = (oE - oM) >> 2;
            int mmax4 = m4A > m4B ? m4A : m4B;
            int o4 = (half ? oM : oA) >> 2;
            int m4 = half ? m4B : m4A;
            float4 acc = make_float4(0.f, 0.f, 0.f, 0.f);
            for (int j4 = 0; j4 < mmax4; j4++) {
                bool val = (j4 < m4);
                int idx = val ? (o4 + j4) : 0;
                unsigned int srcs = esrcW[idx];
                float4 ws = wn4[idx];
                if (!val) { srcs = (unsigned int)node * 0x01010101u;
                            ws = make_float4(0.f, 0.f, 0.f, 0.f); }
                int s0 =  srcs        & 255, s1 = (srcs >> 8)  & 255;
                int s2 = (srcs >> 16) & 255, s3 = (srcs >> 24) & 255;
                float4 v0 = XS[s0 * 32 + physX(s0, c4)];
                float4 v1 = XS[s1 * 32 + physX(s1, c4)];
                float4 v2 = XS[s2 * 32 + physX(s2, c4)];
                float4 v3 = XS[s3 * 32 + physX(s3, c4)];
                acc.x += ws.x * v0.x; acc.y += ws.x * v0.y;
                acc.z += ws.x * v0.z; acc.w += ws.x * v0.w;
                acc.x += ws.y * v1.x; acc.y += ws.y * v1.y;
                acc.z += ws.y * v1.z; acc.w += ws.y * v1.w;
                acc.x += ws.z * v2.x; acc.y += ws.z * v2.y;
                acc.z += ws.z * v2.z; acc.w += ws.z * v2.w;
                acc.x += ws.w * v3.x; acc.y += ws.w * v3.y;
                acc.z += ws.w * v3.z; acc.w += ws.w * v3.w;
            }
            float wsf = selfnL[node];                 // self-loop LAST (r5 order)
            float4 sv = XS[node * 32 + physX(node, c4)];
            acc.x += wsf * sv.x; acc.y += wsf * sv.y;
            acc.z += wsf * sv.z; acc.w += wsf * sv.w;
            accA[it] = acc;
        }
        __syncthreads();                              // all X reads done
        // write AGG (GEMM layout) over the X region
#pragma unroll
        for (int it = 0; it < 16; it++) {
            int node = 2 * (wid * 16 + it) + half;
            XS[node * 32 + physA(node, c4)] = accA[it];
        }
        __syncthreads();

        // ---- GEMM 256x128 @ 128x128, k strictly ascending (exact r5 chains) ----
        int rg = t & 31, cg = t >> 5;                 // rows rg*8..+7, cols cg*8..+7
        float a2[8][8];
#pragma unroll
        for (int i = 0; i < 8; i++)
#pragma unroll
            for (int j = 0; j < 8; j++) a2[i][j] = 0.f;
        for (int k4 = 0; k4 < 32; k4++) {
            float4 a4[8];
#pragma unroll
            for (int i = 0; i < 8; i++)
                a4[i] = XS[(rg * 8 + i) * 32 + physA(rg * 8 + i, k4)];
            float4 wv[8];
#pragma unroll
            for (int kw = 0; kw < 4; kw++) {
                const float4* wp = ((const float4*)(W + (size_t)(k4 * 4 + kw) * HID)) + cg * 2;
                wv[kw * 2]     = wp[0];
                wv[kw * 2 + 1] = wp[1];
            }
#pragma unroll
            for (int kw = 0; kw < 4; kw++) {
#pragma unroll
                for (int i = 0; i < 8; i++) {
                    float a = (kw == 0) ? a4[i].x : (kw == 1) ? a4[i].y
                            : (kw == 2) ? a4[i].z : a4[i].w;
                    a2[i][0] += a * wv[kw * 2].x;     a2[i][1] += a * wv[kw * 2].y;
                    a2[i][2] += a * wv[kw * 2].z;     a2[i][3] += a * wv[kw * 2].w;
                    a2[i][4] += a * wv[kw * 2 + 1].x; a2[i][5] += a * wv[kw * 2 + 1].y;
                    a2[i][6] += a * wv[kw * 2 + 1].z; a2[i][7] += a * wv[kw * 2 + 1].w;
                }
            }
        }
        float4 bv0 = *(((const float4*)bias) + cg * 2);
        float4 bv1 = *(((const float4*)bias) + cg * 2 + 1);
        float4 o0[8], o1[8];
#pragma unroll
        for (int i = 0; i < 8; i++) {
            o0[i].x = tanhf(a2[i][0] + bv0.x); o0[i].y = tanhf(a2[i][1] + bv0.y);
            o0[i].z = tanhf(a2[i][2] + bv0.z); o0[i].w = tanhf(a2[i][3] + bv0.w);
            o1[i].x = tanhf(a2[i][4] + bv1.x); o1[i].y = tanhf(a2[i][5] + bv1.y);
            o1[i].z = tanhf(a2[i][6] + bv1.z); o1[i].w = tanhf(a2[i][7] + bv1.w);
        }
        __syncthreads();                              // AGG fully consumed
#pragma unroll
        for (int i = 0; i < 8; i++) {
            int rl = rg * 8 + i;
            XS[rl * 32 + physX(rl, cg * 2)]     = o0[i];
            XS[rl * 32 + physX(rl, cg * 2 + 1)] = o1[i];
        }
        __syncthreads();
        // coalesced copy-out XS -> Xout (global)
        for (int i = t; i < NPG * 32; i += 512) {
            int row = i >> 5, cc = i & 31;
            ((float4*)Xout)[(size_t)g * NPG * 32 + i] = XS[row * 32 + physX(row, cc)];
        }
        // no sync needed: next phase only READS XS
    }

    // ---- layer 3 scalar: t3 = X2-row . W3 (r5's exact 4-part structure) ----
    {
        int n = t >> 1, h = t & 1;
        const float4* w4 = (const float4*)W3;
        const float4* rb = XS + n * 32;
        float a = 0.f, b = 0.f;
#pragma unroll
        for (int q = 0; q < 8; q++) {
            float4 v = rb[physX(n, h * 8 + q)];
            float4 ww = w4[h * 8 + q];
            a += v.x * ww.x + v.y * ww.y + v.z * ww.z + v.w * ww.w;
        }
#pragma unroll
        for (int q = 0; q < 8; q++) {
            float4 v = rb[physX(n, (h + 2) * 8 + q)];
            float4 ww = w4[(h + 2) * 8 + q];
            b += v.x * ww.x + v.y * ww.y + v.z * ww.z + v.w * ww.w;
        }
        float s = a + b;
        float so = __shfl_down(s, 1);
        if (h == 0) t3s[n] = s + so;
    }
    __syncthreads();

    // ---- key = tanh(agg(t3) + b3), then stable top-60 rank ----
    if (t < NPG) {
        int o = offL[t], m2 = mLn[t];
        float s = 0.f;
        for (int i = 0; i < m2; i++)
            s += wnL[o + i] * t3s[esrcL[o + i]];
        s += selfnL[t] * t3s[t];
        float key = tanhf(s + b3[0]);
        keyL[t] = key;
        keyb[g * NPG + t] = key;
    }
    __syncthreads();
    if (t < NPG) {
        float ki = keyL[t];
        int rank = 0;
        for (int j = 0; j < NPG; j++) {
            float kj = keyL[j];
            rank += (kj > ki) || (kj == ki && j < t);
        }
        if (rank < KTOP) sel[g * KTOP + rank] = g * NPG + t;
    }
}

// ---------------- conv/MLP head: one block per graph (unchanged from r5) ----------------
__global__ __launch_bounds__(256) void k_head(const float* __restrict__ X0,
                                              const float* __restrict__ X1,
                                              const float* __restrict__ X2,
                                              const float* __restrict__ key,
                                              const int* __restrict__ sel,
                                              const float* __restrict__ c1w,
                                              const float* __restrict__ c1b,
                                              const float* __restrict__ c2w,
                                              const float* __restrict__ c2b,
                                              const float* __restrict__ l1w,
                                              const float* __restrict__ l1b,
                                              const float* __restrict__ l2w,
                                              const float* __restrict__ l2b,
                                              float* __restrict__ out) {
    __shared__ __align__(16) float pch[KTOP * 132];
    __shared__ __align__(16) float w1s[16 * 132];
    __shared__ int   seln[KTOP];
    __shared__ float selk[KTOP];
    __shared__ float c1s[16 * KTOP];
    __shared__ float mps[16 * 30];
    __shared__ float w2s[32 * 80];
    __shared__ float yb[832];
    __shared__ float l1p[256];
    __shared__ float l1v[128];

    int g = blockIdx.x, t = threadIdx.x;
    if (t < KTOP) {
        int nd = sel[g * KTOP + t];
        seln[t] = nd;
        selk[t] = key[nd];
    }

    float acc1[4] = {0.f, 0.f, 0.f, 0.f};
    for (int tc = 0; tc < 3; tc++) {
        const float* Xsrc = (tc == 0) ? X0 : ((tc == 1) ? X1 : X2);
        __syncthreads();
        for (int i = t; i < KTOP * 32; i += 256) {
            int k = i >> 5, q = i & 31;
            int nd = seln[k];
            *((float4*)&pch[k * 132 + q * 4]) = ((const float4*)Xsrc)[(size_t)nd * 32 + q];
        }
        for (int i = t; i < 16 * 128; i += 256) {
            int ch = i >> 7, tt = i & 127;
            w1s[ch * 132 + tt] = c1w[ch * TLDIM + tc * 128 + tt];
        }
        __syncthreads();
#pragma unroll
        for (int it = 0; it < 4; it++) {
            int e = it * 256 + t;
            if (e < 960) {
                int k = e >> 4, ch = e & 15;
                const float* pr = &pch[k * 132];
                const float* wr = &w1s[ch * 132];
                float s = 0.f;
#pragma unroll
                for (int q = 0; q < 32; q++) {
                    float4 pv = *((float4*)&pr[q * 4]);
                    float4 wv = *((float4*)&wr[q * 4]);
                    s += pv.x * wv.x + pv.y * wv.y + pv.z * wv.z + pv.w * wv.w;
                }
                acc1[it] += s;
            }
        }
    }
    __syncthreads();
#pragma unroll
    for (int it = 0; it < 4; it++) {
        int e = it * 256 + t;
        if (e < 960) {
            int k = e >> 4, ch = e & 15;
            float v = acc1[it] + selk[k] * c1w[ch * TLDIM + 384] + c1b[ch];
            c1s[ch * KTOP + k] = fmaxf(v, 0.f);
        }
    }
    for (int i = t; i < 2560; i += 256) w2s[i] = c2w[i];
    __syncthreads();
    for (int i = t; i < 480; i += 256) {
        int ch = i / 30, p = i - ch * 30;
        mps[ch * 30 + p] = fmaxf(c1s[ch * KTOP + 2 * p], c1s[ch * KTOP + 2 * p + 1]);
    }
    __syncthreads();
    for (int e = t; e < 832; e += 256) {
        int oc = e / 26, q = e - oc * 26;
        float s = 0.f;
#pragma unroll
        for (int ic = 0; ic < 16; ic++) {
            const float* mr = &mps[ic * 30 + q];
            const float* wr = &w2s[oc * 80 + ic * 5];
#pragma unroll
            for (int j = 0; j < 5; j++) s += mr[j] * wr[j];
        }
        yb[e] = fmaxf(s + c2b[oc], 0.f);
    }
    __syncthreads();
    {
        int u = t & 127, h = t >> 7;
        float s = 0.f;
        for (int d = h * 416; d < h * 416 + 416; d++) s += yb[d] * l1w[d * 128 + u];
        l1p[t] = s;
    }
    __syncthreads();
    if (t < 128) {
        float v = fmaxf(l1p[t] + l1p[t + 128] + l1b[t], 0.f);
        l1v[t] = v * l2w[t];
    }
    __syncthreads();
    if (t < 64) {
        float v = l1v[t] + l1v[t + 64];
        v += __shfl_down(v, 32);
        v += __shfl_down(v, 16);
        v += __shfl_down(v, 8);
        v += __shfl_down(v, 4);
        v += __shfl_down(v, 2);
        v += __shfl_down(v, 1);
        if (t == 0) out[g] = v + l2b[0];
    }
}

extern "C" void kernel_launch(void* const* d_in, const int* in_sizes, int n_in,
                              void* d_out, int out_size, void* d_ws, size_t ws_size,
                              hipStream_t stream) {
    (void)in_sizes; (void)n_in; (void)out_size; (void)ws_size;
    const float* zt  = (const float*)d_in[0];
    const float* W0  = (const float*)d_in[1];
    const float* b0  = (const float*)d_in[2];
    const float* W1  = (const float*)d_in[3];
    const float* b1  = (const float*)d_in[4];
    const float* W2  = (const float*)d_in[5];
    const float* b2  = (const float*)d_in[6];
    const float* W3  = (const float*)d_in[7];
    const float* b3  = (const float*)d_in[8];
    const float* c1w = (const float*)d_in[9];
    const float* c1b = (const float*)d_in[10];
    const float* c2w = (const float*)d_in[11];
    const float* c2b = (const float*)d_in[12];
    const float* l1w = (const float*)d_in[13];
    const float* l1b = (const float*)d_in[14];
    const float* l2w = (const float*)d_in[15];
    const float* l2b = (const float*)d_in[16];
    const float* ew  = (const float*)d_in[17];
    const int*   z   = (const int*)d_in[18];
    const int*   ei  = (const int*)d_in[19];
    float* out = (float*)d_out;

    char* wsp = (char*)d_ws;
    size_t off = 0;
    auto alloc = [&](size_t bytes) -> void* {
        void* p = wsp + off;
        off += (bytes + 255) & ~(size_t)255;
        return p;
    };
    float* X0   = (float*)alloc((size_t)NTOT * HID * 4);
    float* X1   = (float*)alloc((size_t)NTOT * HID * 4);
    float* X2   = (float*)alloc((size_t)NTOT * HID * 4);
    float* keyb = (float*)alloc((size_t)NTOT * 4);
    int*   sel  = (int*)  alloc((size_t)BGR * KTOP * 4);

    k_gnn <<<BGR, dim3(512), 0, stream>>>(zt, z, ei, ew,
                                          W0, b0, W1, b1, W2, b2, W3, b3,
                                          X0, X1, X2, keyb, sel);
    k_head<<<BGR, dim3(256), 0, stream>>>(X0, X1, X2, keyb, sel,
                                          c1w, c1b, c2w, c2b,
                                          l1w, l1b, l2w, l2b, out);
}